// Round 4
// baseline (590.319 us; speedup 1.0000x reference)
//
#include <hip/hip_runtime.h>
#include <hip/hip_bf16.h>

// B=2, H=16, L=2048, D=64. BH=32 flattened heads.
// MFMA flash attention, round 4: two-pass.
//  Pass 1 (convert_kernel): fp32/bf16 K, PE_K, V -> bf16 hi/lo (RNE hi + exact
//    residual lo), written ONCE into workspace as exact swizzled LDS images
//    (24KB per (bh,kt) chunk; V pre-transposed). Removes the 16.5x-redundant
//    per-block conversion and the uncoalesced V gather from the hot loop.
//  Pass 2 (attn_slim): staging = 6 coalesced uint4 loads (prefetched under
//    previous tile's compute) + 6 linear ds_write_b128. Everything else
//    (MFMA split-precision scores/PV, online softmax) as round 3.
//  If ws_size is too small: fall back to the round-3 kernel (attn_fb).
// Runtime dtype detection kept (flag in d_ws); each templated kernel
// early-exits unless the flag matches. Graph-safe: no host sync, fixed
// launch set per ws_size. mask input (d_in[5]) is pure causal -> analytic.

typedef unsigned short u16;
typedef unsigned int   u32;
typedef __attribute__((ext_vector_type(8))) short bf16x8;  // 8 bf16 (4 VGPR)
typedef __attribute__((ext_vector_type(4))) float f32x4;   // MFMA acc

#define L_SEQ 2048
#define D_DIM 64
#define BQ    64            // q rows per block = 4 waves x 16
#define BK    32            // keys per tile
#define NQT   (L_SEQ / BQ)  // 32 q-tiles per head
#define NKT_ALL (L_SEQ / BK)            // 64 key-tiles per head
#define CHUNK_U16 12288                 // 24KB chunk: Kt[4096] Et[4096] Vt[4096]

__device__ __forceinline__ float bf2f(u32 lo16) {
    u32 u = lo16 << 16; float f; __builtin_memcpy(&f, &u, 4); return f;
}
__device__ __forceinline__ u16 f2bf_rne(float x) {
    __hip_bfloat16 h = __float2bfloat16(x); u16 b; __builtin_memcpy(&b, &h, 2); return b;
}

__global__ void detect_dtype_kernel(const u16* __restrict__ q, int* __restrict__ flag) {
    const int lane = threadIdx.x;             // 64 threads, 1 block
    float x = fabsf(bf2f((u32)q[lane]));
    bool big = !(x <= 100.f);                 // fp32 mantissa bits look like wild bf16
    unsigned long long m = __ballot(big);
    if (lane == 0) *flag = (m != 0ull) ? 1 : 0;  // 1 = fp32, 0 = bf16
}

__device__ __forceinline__ uint4 pack8u(const u16* h) {
    uint4 v;
    v.x = (u32)h[0] | ((u32)h[1] << 16);
    v.y = (u32)h[2] | ((u32)h[3] << 16);
    v.z = (u32)h[4] | ((u32)h[5] << 16);
    v.w = (u32)h[6] | ((u32)h[7] << 16);
    return v;
}

// ---- truncating hi/lo split (hot path: P only) ----
__device__ __forceinline__ void split_pack(const float* x, uint4& h, uint4& l) {
    u32 xb[8], rb[8];
#pragma unroll
    for (int j = 0; j < 8; ++j) {
        __builtin_memcpy(&xb[j], &x[j], 4);
        u32 hb = xb[j] & 0xffff0000u;
        float hf; __builtin_memcpy(&hf, &hb, 4);
        float r = x[j] - hf;                  // exact residual of truncation
        __builtin_memcpy(&rb[j], &r, 4);
    }
    h.x = (xb[0] >> 16) | (xb[1] & 0xffff0000u);
    h.y = (xb[2] >> 16) | (xb[3] & 0xffff0000u);
    h.z = (xb[4] >> 16) | (xb[5] & 0xffff0000u);
    h.w = (xb[6] >> 16) | (xb[7] & 0xffff0000u);
    l.x = (rb[0] >> 16) | (rb[1] & 0xffff0000u);
    l.y = (rb[2] >> 16) | (rb[3] & 0xffff0000u);
    l.z = (rb[4] >> 16) | (rb[5] & 0xffff0000u);
    l.w = (rb[6] >> 16) | (rb[7] & 0xffff0000u);
}

// ---- RNE hi + residual lo (pre-pass / prologue; better margin) ----
__device__ __forceinline__ void split_pack_rne(const float* x, uint4& h, uint4& l) {
    u16 hh[8], ll[8];
#pragma unroll
    for (int j = 0; j < 8; ++j) {
        u16 hb = f2bf_rne(x[j]);
        float r = x[j] - bf2f((u32)hb);
        u32 rb; __builtin_memcpy(&rb, &r, 4);
        hh[j] = hb; ll[j] = (u16)(rb >> 16);
    }
    h = pack8u(hh); l = pack8u(ll);
}

template<bool IS_F32>
__device__ __forceinline__ void unpack8(const uint4& a, const uint4& b, float* x) {
    if (IS_F32) {
        u32 w[8] = {a.x, a.y, a.z, a.w, b.x, b.y, b.z, b.w};
#pragma unroll
        for (int j = 0; j < 8; ++j) __builtin_memcpy(&x[j], &w[j], 4);
    } else {
        u32 w[4] = {a.x, a.y, a.z, a.w};
#pragma unroll
        for (int j = 0; j < 4; ++j) {
            x[2*j]   = bf2f(w[j] & 0xffffu);
            x[2*j+1] = bf2f(w[j] >> 16);
        }
    }
}

struct Stage { uint4 k0, k1, e0, e1; u32 v[8]; };  // bf16 path uses k0/e0 only

template<bool IS_F32>
__device__ __forceinline__ void issue_loads(
        const void* Kv, const void* Ev, const void* Vv,
        size_t base, int kbase, int r, int j8, int d, int kg, Stage& R) {
    const size_t ke_off = base + (size_t)(kbase + r) * D_DIM + j8 * 8;
    const size_t v_off  = base + (size_t)(kbase + kg * 8) * D_DIM + d;
    if (IS_F32) {
        const uint4* kp = (const uint4*)((const float*)Kv + ke_off);
        R.k0 = kp[0]; R.k1 = kp[1];
        const uint4* ep = (const uint4*)((const float*)Ev + ke_off);
        R.e0 = ep[0]; R.e1 = ep[1];
        const u32* vp = (const u32*)((const float*)Vv + v_off);
#pragma unroll
        for (int j = 0; j < 8; ++j) R.v[j] = vp[j * D_DIM];   // one dim, 8 keys
    } else {
        R.k0 = *(const uint4*)((const u16*)Kv + ke_off);
        R.e0 = *(const uint4*)((const u16*)Ev + ke_off);
        const u16* vp = (const u16*)Vv + v_off;
#pragma unroll
        for (int j = 0; j < 8; ++j) R.v[j] = (u32)vp[j * D_DIM];
    }
}

#define MFMA(a, b, c) __builtin_amdgcn_mfma_f32_16x16x32_bf16((a), (b), (c), 0, 0, 0)

// ==================== pass 1: convert K / PE_K / V once ====================
template<bool IS_F32>
__global__ __launch_bounds__(256) void convert_kernel(
    const void* __restrict__ Kv, const void* __restrict__ Vv,
    const void* __restrict__ PKv, u16* __restrict__ chunks,
    const int* __restrict__ flag)
{
    if (((*flag) != 0) != IS_F32) return;
    const int kt = blockIdx.x;               // 0..63
    const int bh = blockIdx.y;               // 0..31
    const int t  = threadIdx.x;
    const size_t base = (size_t)bh * L_SEQ * D_DIM;
    u16* chunk = chunks + ((size_t)bh * NKT_ALL + kt) * CHUNK_U16;
    const int r  = t >> 3, j8 = t & 7;       // K/E: row, 8-elem chunk
    const int d  = t & 63, kg = t >> 6;      // V: dim, key chunk

    Stage R;
    issue_loads<IS_F32>(Kv, PKv, Vv, base, kt * BK, r, j8, d, kg, R);

    float x[8]; uint4 hp, lp;
    const int ke_wo = r * 128 + (j8 ^ (r & 7)) * 8;       // swizzled slot
    unpack8<IS_F32>(R.k0, R.k1, x); split_pack_rne(x, hp, lp);
    *(uint4*)(chunk + ke_wo)      = hp;
    *(uint4*)(chunk + ke_wo + 64) = lp;
    unpack8<IS_F32>(R.e0, R.e1, x); split_pack_rne(x, hp, lp);
    *(uint4*)(chunk + 4096 + ke_wo)      = hp;
    *(uint4*)(chunk + 4096 + ke_wo + 64) = lp;
#pragma unroll
    for (int j = 0; j < 8; ++j) {
        if (IS_F32) __builtin_memcpy(&x[j], &R.v[j], 4);
        else        x[j] = bf2f(R.v[j]);
    }
    split_pack_rne(x, hp, lp);
    const int rr = d >> 1;
    const int sh = (4 * (d & 1) + kg) ^ (rr & 7);
    const int v_wo = 8192 + rr * 128 + sh * 8;
    *(uint4*)(chunk + v_wo)      = hp;
    *(uint4*)(chunk + v_wo + 64) = lp;
}

// ==================== pass 2: slim attention ====================
template<bool IS_F32>
__global__ __launch_bounds__(256, 4) void attn_slim(
    const void* __restrict__ Qv, const void* __restrict__ PQv,
    const u16* __restrict__ chunks, void* __restrict__ Ov,
    const int* __restrict__ flag)
{
    if (((*flag) != 0) != IS_F32) return;

    const int qt   = NQT - 1 - (int)blockIdx.x;  // heaviest q-tiles dispatch first
    const int bh   = blockIdx.y;
    const int t    = threadIdx.x;
    const int w    = t >> 6;
    const int lane = t & 63;
    const int g    = lane >> 4;
    const int c    = lane & 15;
    const size_t base = (size_t)bh * L_SEQ * D_DIM;
    const int qb_w = qt * BQ + w * 16;

    __shared__ __align__(16) u16 KEV[CHUNK_U16];      // 24 KB: Kt | Et | Vt images
    __shared__ __align__(16) u16 Pb[4][8 * 128];      // 8 KB per-wave P
    const u16* Kt = KEV;
    const u16* Et = KEV + 4096;
    const u16* Vt = KEV + 8192;

    // ---- Q & PE_Q A-fragments (pre-scaled by 1/8; RNE hi + residual lo) ----
    bf16x8 qa_h[4], qa_l[4];                 // ch 0,1 = Q d0=0,32 ; ch 2,3 = PE_Q
    {
        const int qrow = qb_w + c;
#pragma unroll
        for (int ch = 0; ch < 4; ++ch) {
            const void* src = (ch < 2) ? Qv : PQv;
            const int d0 = (ch & 1) * 32 + 8 * g;
            const size_t off = base + (size_t)qrow * D_DIM + d0;
            float x[8];
            if (IS_F32) {
                const uint4* gp = (const uint4*)((const float*)src + off);
                unpack8<true>(gp[0], gp[1], x);
            } else {
                uint4 a = *(const uint4*)((const u16*)src + off);
                unpack8<false>(a, a, x);
            }
#pragma unroll
            for (int j = 0; j < 8; ++j) x[j] *= 0.125f;
            uint4 hp, lp; split_pack_rne(x, hp, lp);
            u32 hw[4] = {hp.x, hp.y, hp.z, hp.w}, lw[4] = {lp.x, lp.y, lp.z, lp.w};
#pragma unroll
            for (int j = 0; j < 4; ++j) {
                qa_h[ch][2*j]   = (short)(hw[j] & 0xffffu);
                qa_h[ch][2*j+1] = (short)(hw[j] >> 16);
                qa_l[ch][2*j]   = (short)(lw[j] & 0xffffu);
                qa_l[ch][2*j+1] = (short)(lw[j] >> 16);
            }
        }
    }

    float mr[4], lr[4];
    f32x4 acc[4];
#pragma unroll
    for (int i = 0; i < 4; ++i) { mr[i] = -INFINITY; lr[i] = 0.f; }
#pragma unroll
    for (int df = 0; df < 4; ++df) acc[df] = (f32x4){0.f, 0.f, 0.f, 0.f};

    const int nkt = 2 * qt + 2;
    const u16* hbase = chunks + (size_t)bh * NKT_ALL * CHUNK_U16;

    uint4 R[6];                              // prefetched tile image (96B/thread)
    {
        const uint4* src = (const uint4*)hbase;     // tile 0
#pragma unroll
        for (int i = 0; i < 6; ++i) R[i] = src[i * 256 + t];
    }

    for (int kt = 0; kt < nkt; ++kt) {
        const int kbase = kt * BK;
        __syncthreads();                     // (A) prev tile's compute done
#pragma unroll
        for (int i = 0; i < 6; ++i)          // 6 linear ds_write_b128
            ((uint4*)KEV)[i * 256 + t] = R[i];
        __syncthreads();                     // (B) staging visible to all waves

        if (kt + 1 < nkt) {                  // prefetch next tile under compute
            const uint4* src = (const uint4*)(hbase + (size_t)(kt + 1) * CHUNK_U16);
#pragma unroll
            for (int i = 0; i < 6; ++i) R[i] = src[i * 256 + t];
        }

        if (kbase <= qb_w + 15) {            // wave-uniform: tile has unmasked keys
            const bool do1 = (kbase + 16 <= qb_w + 15);
            const int c7 = c & 7;
            // ---- scores: S = (Q.K^T + PEq.PEk^T) * 1/8, split precision ----
            f32x4 s0 = {0,0,0,0}, s1 = {0,0,0,0};
#pragma unroll
            for (int ch = 0; ch < 4; ++ch) {
                const u16* Bp = (ch < 2) ? Kt : Et;
                const int sh = ((((ch & 1) * 4 + g) ^ c7)) * 8;
                const u16* r0 = Bp + c * 128;
                bf16x8 b0h = *(const bf16x8*)(r0 + sh);
                bf16x8 b0l = *(const bf16x8*)(r0 + sh + 64);
                s0 = MFMA(qa_h[ch], b0h, s0);
                s0 = MFMA(qa_h[ch], b0l, s0);
                s0 = MFMA(qa_l[ch], b0h, s0);
                if (do1) {
                    const u16* r1 = Bp + (c + 16) * 128;   // (c+16)&7 == c&7
                    bf16x8 b1h = *(const bf16x8*)(r1 + sh);
                    bf16x8 b1l = *(const bf16x8*)(r1 + sh + 64);
                    s1 = MFMA(qa_h[ch], b1h, s1);
                    s1 = MFMA(qa_h[ch], b1l, s1);
                    s1 = MFMA(qa_l[ch], b1h, s1);
                }
            }
            // ---- causal mask (C/D layout: row = 4g+i, col = c) ----
#pragma unroll
            for (int i = 0; i < 4; ++i) {
                const int r = qb_w + 4 * g + i;
                if (kbase + c > r)                s0[i] = -INFINITY;
                if (!do1 || kbase + 16 + c > r)   s1[i] = -INFINITY;
            }
            // ---- row max across the 16 lanes of this group ----
            float vm[4];
#pragma unroll
            for (int i = 0; i < 4; ++i) vm[i] = fmaxf(s0[i], s1[i]);
#pragma unroll
            for (int off = 1; off < 16; off <<= 1) {
#pragma unroll
                for (int i = 0; i < 4; ++i) vm[i] = fmaxf(vm[i], __shfl_xor(vm[i], off));
            }
            float al[4];
#pragma unroll
            for (int i = 0; i < 4; ++i) {
                float mn = fmaxf(mr[i], vm[i]);
                al[i] = __expf(mr[i] - mn);         // exp(-inf)=0 on first tile
                mr[i] = mn;
            }
            f32x4 p0, p1;
#pragma unroll
            for (int i = 0; i < 4; ++i) {
                p0[i] = __expf(s0[i] - mr[i]);      // masked -> exp(-inf)=0
                p1[i] = __expf(s1[i] - mr[i]);
            }
            float rs[4];
#pragma unroll
            for (int i = 0; i < 4; ++i) rs[i] = p0[i] + p1[i];
#pragma unroll
            for (int off = 1; off < 16; off <<= 1) {
#pragma unroll
                for (int i = 0; i < 4; ++i) rs[i] += __shfl_xor(rs[i], off);
            }
#pragma unroll
            for (int i = 0; i < 4; ++i) lr[i] = lr[i] * al[i] + rs[i];
#pragma unroll
            for (int df = 0; df < 4; ++df) {
#pragma unroll
                for (int i = 0; i < 4; ++i) acc[df][i] *= al[i];
            }
            // ---- P -> per-wave LDS (trunc hi/lo) to convert C- -> A-layout ----
            u16* pp = (u16*)Pb[w];
#pragma unroll
            for (int i = 0; i < 4; ++i) {
                const int rrp = 2 * g + (i >> 1);
                const int sb  = 4 * (i & 1);
                const int h3  = rrp & 7;
                u16* rowp = pp + rrp * 128 + c7;
                const float x0 = p0[i];
                const float x1 = p1[i];
                u32 b0; __builtin_memcpy(&b0, &x0, 4);
                u32 h0 = b0 & 0xffff0000u; float h0f; __builtin_memcpy(&h0f, &h0, 4);
                float l0f = x0 - h0f; u32 l0; __builtin_memcpy(&l0, &l0f, 4);
                u32 b1; __builtin_memcpy(&b1, &x1, 4);
                u32 h1 = b1 & 0xffff0000u; float h1f; __builtin_memcpy(&h1f, &h1, 4);
                float l1f = x1 - h1f; u32 l1; __builtin_memcpy(&l1, &l1f, 4);
                const int s0i = (sb + (c >> 3)) ^ h3;
                const int s1i = (sb + 2 + (c >> 3)) ^ h3;
                rowp[s0i * 8]       = (u16)(b0 >> 16);
                rowp[(8 + s0i) * 8] = (u16)(l0 >> 16);
                rowp[s1i * 8]       = (u16)(b1 >> 16);
                rowp[(8 + s1i) * 8] = (u16)(l1 >> 16);
            }
            // in-wave ds_write -> ds_read: lockstep wave, compiler inserts lgkmcnt
            const int sv = ((4 * (c & 1) + g) ^ ((c >> 1) & 7)) * 8;  // P & V share formula
            const u16* pw = pp + (c >> 1) * 128;
            bf16x8 pa_h = *(const bf16x8*)(pw + sv);
            bf16x8 pa_l = *(const bf16x8*)(pw + sv + 64);
            // ---- PV: acc += P.V (split precision: PhVh + PhVl + PlVh) ----
#pragma unroll
            for (int df = 0; df < 4; ++df) {
                const u16* vw = Vt + (8 * df + (c >> 1)) * 128;
                bf16x8 vbh = *(const bf16x8*)(vw + sv);
                bf16x8 vbl = *(const bf16x8*)(vw + sv + 64);
                acc[df] = MFMA(pa_h, vbh, acc[df]);
                acc[df] = MFMA(pa_h, vbl, acc[df]);
                acc[df] = MFMA(pa_l, vbh, acc[df]);
            }
        }
    }

    // ---- epilogue ----
    float inv[4];
#pragma unroll
    for (int i = 0; i < 4; ++i) inv[i] = 1.f / lr[i];
    if (IS_F32) {
        float* o = (float*)Ov + base;
#pragma unroll
        for (int df = 0; df < 4; ++df)
#pragma unroll
            for (int i = 0; i < 4; ++i)
                o[(size_t)(qb_w + 4 * g + i) * D_DIM + 16 * df + c] = acc[df][i] * inv[i];
    } else {
        __hip_bfloat16* o = (__hip_bfloat16*)Ov + base;
#pragma unroll
        for (int df = 0; df < 4; ++df)
#pragma unroll
            for (int i = 0; i < 4; ++i)
                o[(size_t)(qb_w + 4 * g + i) * D_DIM + 16 * df + c] =
                    __float2bfloat16(acc[df][i] * inv[i]);
    }
}

// ==================== fallback: round-3 kernel (proven) ====================
template<bool IS_F32>
__global__ __launch_bounds__(256, 4) void attn_fb(
    const void* __restrict__ Qv, const void* __restrict__ Kv,
    const void* __restrict__ Vv, const void* __restrict__ PQv,
    const void* __restrict__ PKv, void* __restrict__ Ov,
    const int* __restrict__ flag)
{
    if (((*flag) != 0) != IS_F32) return;

    const int qt   = NQT - 1 - (int)blockIdx.x;
    const int bh   = blockIdx.y;
    const int t    = threadIdx.x;
    const int w    = t >> 6;
    const int lane = t & 63;
    const int g    = lane >> 4;
    const int c    = lane & 15;
    const size_t base = (size_t)bh * L_SEQ * D_DIM;
    const int qb_w = qt * BQ + w * 16;

    __shared__ __align__(16) u16 Kt[BK * 128];
    __shared__ __align__(16) u16 Et[BK * 128];
    __shared__ __align__(16) u16 Vt[32 * 128];
    __shared__ __align__(16) u16 Pb[4][8 * 128];

    bf16x8 qa_h[4], qa_l[4];
    {
        const int qrow = qb_w + c;
#pragma unroll
        for (int ch = 0; ch < 4; ++ch) {
            const void* src = (ch < 2) ? Qv : PQv;
            const int d0 = (ch & 1) * 32 + 8 * g;
            const size_t off = base + (size_t)qrow * D_DIM + d0;
            float x[8];
            if (IS_F32) {
                const uint4* gp = (const uint4*)((const float*)src + off);
                unpack8<true>(gp[0], gp[1], x);
            } else {
                uint4 a = *(const uint4*)((const u16*)src + off);
                unpack8<false>(a, a, x);
            }
#pragma unroll
            for (int j = 0; j < 8; ++j) x[j] *= 0.125f;
            uint4 hp, lp; split_pack_rne(x, hp, lp);
            u32 hw[4] = {hp.x, hp.y, hp.z, hp.w}, lw[4] = {lp.x, lp.y, lp.z, lp.w};
#pragma unroll
            for (int j = 0; j < 4; ++j) {
                qa_h[ch][2*j]   = (short)(hw[j] & 0xffffu);
                qa_h[ch][2*j+1] = (short)(hw[j] >> 16);
                qa_l[ch][2*j]   = (short)(lw[j] & 0xffffu);
                qa_l[ch][2*j+1] = (short)(lw[j] >> 16);
            }
        }
    }

    float mr[4], lr[4];
    f32x4 acc[4];
#pragma unroll
    for (int i = 0; i < 4; ++i) { mr[i] = -INFINITY; lr[i] = 0.f; }
#pragma unroll
    for (int df = 0; df < 4; ++df) acc[df] = (f32x4){0.f, 0.f, 0.f, 0.f};

    const int nkt = 2 * qt + 2;
    const int r_t  = t >> 3;
    const int j8_t = t & 7;
    const int d_t  = t & 63;
    const int kg_t = t >> 6;
    const int ke_sh = j8_t ^ (r_t & 7);
    const int ke_wo = r_t * 128 + ke_sh * 8;
    const int v_rr  = d_t >> 1;
    const int v_sh  = (4 * (d_t & 1) + kg_t) ^ (v_rr & 7);
    const int v_wo  = v_rr * 128 + v_sh * 8;

    Stage R;
    issue_loads<IS_F32>(Kv, PKv, Vv, base, 0, r_t, j8_t, d_t, kg_t, R);

    for (int kt = 0; kt < nkt; ++kt) {
        const int kbase = kt * BK;
        __syncthreads();
        {
            float x[8]; uint4 hp, lp;
            unpack8<IS_F32>(R.k0, R.k1, x);
            split_pack(x, hp, lp);
            *(uint4*)(Kt + ke_wo)      = hp;
            *(uint4*)(Kt + ke_wo + 64) = lp;
            unpack8<IS_F32>(R.e0, R.e1, x);
            split_pack(x, hp, lp);
            *(uint4*)(Et + ke_wo)      = hp;
            *(uint4*)(Et + ke_wo + 64) = lp;
#pragma unroll
            for (int j = 0; j < 8; ++j) {
                if (IS_F32) __builtin_memcpy(&x[j], &R.v[j], 4);
                else        x[j] = bf2f(R.v[j]);
            }
            split_pack(x, hp, lp);
            *(uint4*)(Vt + v_wo)      = hp;
            *(uint4*)(Vt + v_wo + 64) = lp;
        }
        __syncthreads();

        if (kt + 1 < nkt)
            issue_loads<IS_F32>(Kv, PKv, Vv, base, kbase + BK, r_t, j8_t, d_t, kg_t, R);

        if (kbase <= qb_w + 15) {
            const bool do1 = (kbase + 16 <= qb_w + 15);
            const int c7 = c & 7;
            f32x4 s0 = {0,0,0,0}, s1 = {0,0,0,0};
#pragma unroll
            for (int ch = 0; ch < 4; ++ch) {
                const u16* Bp = (ch < 2) ? Kt : Et;
                const int sh = ((((ch & 1) * 4 + g) ^ c7)) * 8;
                const u16* r0 = Bp + c * 128;
                bf16x8 b0h = *(const bf16x8*)(r0 + sh);
                bf16x8 b0l = *(const bf16x8*)(r0 + sh + 64);
                s0 = MFMA(qa_h[ch], b0h, s0);
                s0 = MFMA(qa_h[ch], b0l, s0);
                s0 = MFMA(qa_l[ch], b0h, s0);
                if (do1) {
                    const u16* r1 = Bp + (c + 16) * 128;
                    bf16x8 b1h = *(const bf16x8*)(r1 + sh);
                    bf16x8 b1l = *(const bf16x8*)(r1 + sh + 64);
                    s1 = MFMA(qa_h[ch], b1h, s1);
                    s1 = MFMA(qa_h[ch], b1l, s1);
                    s1 = MFMA(qa_l[ch], b1h, s1);
                }
            }
#pragma unroll
            for (int i = 0; i < 4; ++i) {
                const int r = qb_w + 4 * g + i;
                if (kbase + c > r)                s0[i] = -INFINITY;
                if (!do1 || kbase + 16 + c > r)   s1[i] = -INFINITY;
            }
            float vm[4];
#pragma unroll
            for (int i = 0; i < 4; ++i) vm[i] = fmaxf(s0[i], s1[i]);
#pragma unroll
            for (int off = 1; off < 16; off <<= 1) {
#pragma unroll
                for (int i = 0; i < 4; ++i) vm[i] = fmaxf(vm[i], __shfl_xor(vm[i], off));
            }
            float al[4];
#pragma unroll
            for (int i = 0; i < 4; ++i) {
                float mn = fmaxf(mr[i], vm[i]);
                al[i] = __expf(mr[i] - mn);
                mr[i] = mn;
            }
            f32x4 p0, p1;
#pragma unroll
            for (int i = 0; i < 4; ++i) {
                p0[i] = __expf(s0[i] - mr[i]);
                p1[i] = __expf(s1[i] - mr[i]);
            }
            float rs[4];
#pragma unroll
            for (int i = 0; i < 4; ++i) rs[i] = p0[i] + p1[i];
#pragma unroll
            for (int off = 1; off < 16; off <<= 1) {
#pragma unroll
                for (int i = 0; i < 4; ++i) rs[i] += __shfl_xor(rs[i], off);
            }
#pragma unroll
            for (int i = 0; i < 4; ++i) lr[i] = lr[i] * al[i] + rs[i];
#pragma unroll
            for (int df = 0; df < 4; ++df) {
#pragma unroll
                for (int i = 0; i < 4; ++i) acc[df][i] *= al[i];
            }
            u16* pp = (u16*)Pb[w];
#pragma unroll
            for (int i = 0; i < 4; ++i) {
                const int rrp = 2 * g + (i >> 1);
                const int sb  = 4 * (i & 1);
                const int h3  = rrp & 7;
                u16* rowp = pp + rrp * 128 + c7;
                const float x0 = p0[i];
                const float x1 = p1[i];
                u32 b0; __builtin_memcpy(&b0, &x0, 4);
                u32 h0 = b0 & 0xffff0000u; float h0f; __builtin_memcpy(&h0f, &h0, 4);
                float l0f = x0 - h0f; u32 l0; __builtin_memcpy(&l0, &l0f, 4);
                u32 b1; __builtin_memcpy(&b1, &x1, 4);
                u32 h1 = b1 & 0xffff0000u; float h1f; __builtin_memcpy(&h1f, &h1, 4);
                float l1f = x1 - h1f; u32 l1; __builtin_memcpy(&l1, &l1f, 4);
                const int s0i = (sb + (c >> 3)) ^ h3;
                const int s1i = (sb + 2 + (c >> 3)) ^ h3;
                rowp[s0i * 8]       = (u16)(b0 >> 16);
                rowp[(8 + s0i) * 8] = (u16)(l0 >> 16);
                rowp[s1i * 8]       = (u16)(b1 >> 16);
                rowp[(8 + s1i) * 8] = (u16)(l1 >> 16);
            }
            const int sv = ((4 * (c & 1) + g) ^ ((c >> 1) & 7)) * 8;
            const u16* pw = pp + (c >> 1) * 128;
            bf16x8 pa_h = *(const bf16x8*)(pw + sv);
            bf16x8 pa_l = *(const bf16x8*)(pw + sv + 64);
#pragma unroll
            for (int df = 0; df < 4; ++df) {
                const u16* vw = Vt + (8 * df + (c >> 1)) * 128;
                bf16x8 vbh = *(const bf16x8*)(vw + sv);
                bf16x8 vbl = *(const bf16x8*)(vw + sv + 64);
                acc[df] = MFMA(pa_h, vbh, acc[df]);
                acc[df] = MFMA(pa_h, vbl, acc[df]);
                acc[df] = MFMA(pa_l, vbh, acc[df]);
            }
        }
    }

    float inv[4];
#pragma unroll
    for (int i = 0; i < 4; ++i) inv[i] = 1.f / lr[i];
    if (IS_F32) {
        float* o = (float*)Ov + base;
#pragma unroll
        for (int df = 0; df < 4; ++df)
#pragma unroll
            for (int i = 0; i < 4; ++i)
                o[(size_t)(qb_w + 4 * g + i) * D_DIM + 16 * df + c] = acc[df][i] * inv[i];
    } else {
        __hip_bfloat16* o = (__hip_bfloat16*)Ov + base;
#pragma unroll
        for (int df = 0; df < 4; ++df)
#pragma unroll
            for (int i = 0; i < 4; ++i)
                o[(size_t)(qb_w + 4 * g + i) * D_DIM + 16 * df + c] =
                    __float2bfloat16(acc[df][i] * inv[i]);
    }
}

extern "C" void kernel_launch(void* const* d_in, const int* in_sizes, int n_in,
                              void* d_out, int out_size, void* d_ws, size_t ws_size,
                              hipStream_t stream) {
    const void* q  = d_in[0];
    const void* k  = d_in[1];
    const void* v  = d_in[2];
    const void* pq = d_in[3];
    const void* pk = d_in[4];
    // d_in[5] = causal mask, recomputed analytically in-kernel.
    int* flag = (int*)d_ws;

    detect_dtype_kernel<<<1, 64, 0, stream>>>((const u16*)q, flag);

    const size_t WS_NEEDED = 256 + (size_t)32 * NKT_ALL * CHUNK_U16 * 2;  // ~50.3 MB
    dim3 grid(NQT, 32);
    if (ws_size >= WS_NEEDED) {
        u16* chunks = (u16*)((char*)d_ws + 256);
        dim3 cg(NKT_ALL, 32);
        convert_kernel<false><<<cg, 256, 0, stream>>>(k, v, pk, chunks, flag);
        convert_kernel<true ><<<cg, 256, 0, stream>>>(k, v, pk, chunks, flag);
        attn_slim<false><<<grid, 256, 0, stream>>>(q, pq, chunks, d_out, flag);
        attn_slim<true ><<<grid, 256, 0, stream>>>(q, pq, chunks, d_out, flag);
    } else {
        attn_fb<false><<<grid, 256, 0, stream>>>(q, k, v, pq, pk, d_out, flag);
        attn_fb<true ><<<grid, 256, 0, stream>>>(q, k, v, pq, pk, d_out, flag);
    }
}

// Round 5
// 304.216 us; speedup vs baseline: 1.9405x; 1.9405x over previous
//
#include <hip/hip_runtime.h>
#include <hip/hip_bf16.h>

// B=2, H=16, L=2048, D=64. BH=32 flattened heads.
// MFMA flash attention, round 5: paired q-tiles sharing one K-sweep.
//  - Round-4's two-pass workspace REGRESSED (HBM writeback storm) -> reverted
//    to round-3's in-kernel convert structure (proven 324us hot).
//  - New: 512-thread blocks, 8 waves. Waves 0-3 compute q-tile qa (light),
//    waves 4-7 compute q-tile 31-qa (heavy); both consume the SAME staged
//    K/PE_K/V tiles -> one k-sweep serves 128 q-rows (-26% staging) and block
//    durations compress from [2..64] to [34..64] trips (tail removal).
//  - (blockIdx.x + bh)&15 rotation interleaves heavy/light pairs across the
//    dispatch order so co-resident blocks on a CU balance (~84-112 trips/CU).
//  - Staging roles: waves 0-3 stage K+PE (heavy stage, light compute),
//    waves 4-7 stage V (light stage, heavy compute).
// Per-wave compute / LDS swizzle formulas byte-identical to round 3.
// Runtime dtype detection kept (flag in d_ws); both instantiations launch,
// wrong one early-exits. mask input (d_in[5]) is pure causal -> analytic.

typedef unsigned short u16;
typedef unsigned int   u32;
typedef __attribute__((ext_vector_type(8))) short bf16x8;  // 8 bf16 (4 VGPR)
typedef __attribute__((ext_vector_type(4))) float f32x4;   // MFMA acc

#define L_SEQ 2048
#define D_DIM 64
#define BQ    64            // q rows per tile = 4 waves x 16
#define BK    32            // keys per tile
#define NQT   (L_SEQ / BQ)  // 32 q-tiles per head

__device__ __forceinline__ float bf2f(u32 lo16) {
    u32 u = lo16 << 16; float f; __builtin_memcpy(&f, &u, 4); return f;
}

__global__ void detect_dtype_kernel(const u16* __restrict__ q, int* __restrict__ flag) {
    const int lane = threadIdx.x;             // 64 threads, 1 block
    float x = fabsf(bf2f((u32)q[lane]));
    bool big = !(x <= 100.f);                 // fp32 mantissa bits look like wild bf16
    unsigned long long m = __ballot(big);
    if (lane == 0) *flag = (m != 0ull) ? 1 : 0;  // 1 = fp32, 0 = bf16
}

// ---- truncating hi/lo split of 8 f32 -> packed bf16 uint4 pair ----
__device__ __forceinline__ void split_pack(const float* x, uint4& h, uint4& l) {
    u32 xb[8], rb[8];
#pragma unroll
    for (int j = 0; j < 8; ++j) {
        __builtin_memcpy(&xb[j], &x[j], 4);
        u32 hb = xb[j] & 0xffff0000u;
        float hf; __builtin_memcpy(&hf, &hb, 4);
        float r = x[j] - hf;                  // exact residual of truncation
        __builtin_memcpy(&rb[j], &r, 4);
    }
    h.x = (xb[0] >> 16) | (xb[1] & 0xffff0000u);
    h.y = (xb[2] >> 16) | (xb[3] & 0xffff0000u);
    h.z = (xb[4] >> 16) | (xb[5] & 0xffff0000u);
    h.w = (xb[6] >> 16) | (xb[7] & 0xffff0000u);
    l.x = (rb[0] >> 16) | (rb[1] & 0xffff0000u);
    l.y = (rb[2] >> 16) | (rb[3] & 0xffff0000u);
    l.z = (rb[4] >> 16) | (rb[5] & 0xffff0000u);
    l.w = (rb[6] >> 16) | (rb[7] & 0xffff0000u);
}

template<bool IS_F32>
__device__ __forceinline__ void unpack8(const uint4& a, const uint4& b, float* x) {
    if (IS_F32) {
        u32 w[8] = {a.x, a.y, a.z, a.w, b.x, b.y, b.z, b.w};
#pragma unroll
        for (int j = 0; j < 8; ++j) __builtin_memcpy(&x[j], &w[j], 4);
    } else {
        u32 w[4] = {a.x, a.y, a.z, a.w};
#pragma unroll
        for (int j = 0; j < 4; ++j) {
            x[2*j]   = bf2f(w[j] & 0xffffu);
            x[2*j+1] = bf2f(w[j] >> 16);
        }
    }
}

struct StKE { uint4 k0, k1, e0, e1; };   // bf16 path uses k0/e0 only
struct StV  { u32 v[8]; };

template<bool IS_F32>
__device__ __forceinline__ void issue_ke(const void* Kv, const void* Ev,
        size_t base, int kbase, int r, int j8, StKE& R) {
    const size_t off = base + (size_t)(kbase + r) * D_DIM + j8 * 8;
    if (IS_F32) {
        const uint4* kp = (const uint4*)((const float*)Kv + off);
        R.k0 = kp[0]; R.k1 = kp[1];
        const uint4* ep = (const uint4*)((const float*)Ev + off);
        R.e0 = ep[0]; R.e1 = ep[1];
    } else {
        R.k0 = *(const uint4*)((const u16*)Kv + off);
        R.e0 = *(const uint4*)((const u16*)Ev + off);
    }
}

template<bool IS_F32>
__device__ __forceinline__ void issue_v(const void* Vv,
        size_t base, int kbase, int d, int kg, StV& R) {
    const size_t off = base + (size_t)(kbase + kg * 8) * D_DIM + d;
    if (IS_F32) {
        const u32* vp = (const u32*)((const float*)Vv + off);
#pragma unroll
        for (int j = 0; j < 8; ++j) R.v[j] = vp[j * D_DIM];   // one dim, 8 keys
    } else {
        const u16* vp = (const u16*)Vv + off;
#pragma unroll
        for (int j = 0; j < 8; ++j) R.v[j] = (u32)vp[j * D_DIM];
    }
}

#define MFMA(a, b, c) __builtin_amdgcn_mfma_f32_16x16x32_bf16((a), (b), (c), 0, 0, 0)

template<bool IS_F32>
__global__ __launch_bounds__(512, 4) void attn_pair(
    const void* __restrict__ Qv, const void* __restrict__ Kv,
    const void* __restrict__ Vv, const void* __restrict__ PQv,
    const void* __restrict__ PKv, void* __restrict__ Ov,
    const int* __restrict__ flag)
{
    if (((*flag) != 0) != IS_F32) return;    // wrong dtype for this instantiation

    const int bh   = blockIdx.y;
    const int qa   = ((int)blockIdx.x + bh) & 15;   // rotation balances CUs
    const int t    = threadIdx.x;
    const int w    = t >> 6;                 // wave 0..7
    const int lane = t & 63;
    const int g    = lane >> 4;              // 16-lane group 0..3
    const int c    = lane & 15;
    const size_t base = (size_t)bh * L_SEQ * D_DIM;
    const int qtile = (w < 4) ? qa : (31 - qa);     // light / heavy q-tile
    const int qb_w  = qtile * BQ + (w & 3) * 16;    // this wave's first q row
    const int nkt   = 64 - 2 * qa;           // heavy tile's k-tile count (covers light)

    // LDS (round-3 swizzled layouts; rows 256B, 16B slots XOR'd):
    __shared__ __align__(16) u16 Kt[BK * 128];        // 8 KB
    __shared__ __align__(16) u16 Et[BK * 128];        // 8 KB
    __shared__ __align__(16) u16 Vt[32 * 128];        // 8 KB
    __shared__ __align__(16) u16 Pb[8][8 * 128];      // 16 KB (per-wave P)
    // total 40 KB -> 2 blocks/CU (16 waves/CU)

    // ---- Q & PE_Q A-fragments (pre-scaled by 1/8; exact power-of-2) ----
    bf16x8 qa_h[4], qa_l[4];                 // ch 0,1 = Q d0=0,32 ; ch 2,3 = PE_Q
    {
        const int qrow = qb_w + c;
#pragma unroll
        for (int ch = 0; ch < 4; ++ch) {
            const void* src = (ch < 2) ? Qv : PQv;
            const int d0 = (ch & 1) * 32 + 8 * g;
            const size_t off = base + (size_t)qrow * D_DIM + d0;
            float x[8];
            if (IS_F32) {
                const uint4* gp = (const uint4*)((const float*)src + off);
                unpack8<true>(gp[0], gp[1], x);
            } else {
                uint4 a = *(const uint4*)((const u16*)src + off);
                unpack8<false>(a, a, x);
            }
#pragma unroll
            for (int j = 0; j < 8; ++j) x[j] *= 0.125f;
            uint4 hp, lp; split_pack(x, hp, lp);
            u32 hw[4] = {hp.x, hp.y, hp.z, hp.w}, lw[4] = {lp.x, lp.y, lp.z, lp.w};
#pragma unroll
            for (int j = 0; j < 4; ++j) {
                qa_h[ch][2*j]   = (short)(hw[j] & 0xffffu);
                qa_h[ch][2*j+1] = (short)(hw[j] >> 16);
                qa_l[ch][2*j]   = (short)(lw[j] & 0xffffu);
                qa_l[ch][2*j+1] = (short)(lw[j] >> 16);
            }
        }
    }

    float mr[4], lr[4];
    f32x4 acc[4];
#pragma unroll
    for (int i = 0; i < 4; ++i) { mr[i] = -INFINITY; lr[i] = 0.f; }
#pragma unroll
    for (int df = 0; df < 4; ++df) acc[df] = (f32x4){0.f, 0.f, 0.f, 0.f};

    // ---- staging roles: waves 0-3 stage K+PE, waves 4-7 stage V ----
    const bool is_ke = (t < 256);
    const int ts   = t & 255;
    const int r_t  = ts >> 3;                // K/E: row (key) 0..31
    const int j8_t = ts & 7;                 // K/E: 8-elem chunk 0..7
    const int d_t  = ts & 63;                // V: dim 0..63
    const int kg_t = (ts >> 6) & 3;          // V: key chunk 0..3
    const int ke_wo = r_t * 128 + (j8_t ^ (r_t & 7)) * 8;           // hi; lo at +64
    const int v_rr  = d_t >> 1;
    const int v_wo  = v_rr * 128 + ((4 * (d_t & 1) + kg_t) ^ (v_rr & 7)) * 8;

    StKE Rke; StV Rv;
    if (is_ke) issue_ke<IS_F32>(Kv, PKv, base, 0, r_t, j8_t, Rke);
    else       issue_v <IS_F32>(Vv, base, 0, d_t, kg_t, Rv);

    for (int kt = 0; kt < nkt; ++kt) {
        const int kbase = kt * BK;
        __syncthreads();                     // (A) prev tile's compute done
        if (is_ke) {                         // convert + write staged K/PE tile
            float x[8]; uint4 hp, lp;
            unpack8<IS_F32>(Rke.k0, Rke.k1, x);
            split_pack(x, hp, lp);
            *(uint4*)(Kt + ke_wo)      = hp;
            *(uint4*)(Kt + ke_wo + 64) = lp;
            unpack8<IS_F32>(Rke.e0, Rke.e1, x);
            split_pack(x, hp, lp);
            *(uint4*)(Et + ke_wo)      = hp;
            *(uint4*)(Et + ke_wo + 64) = lp;
        } else {                             // convert + write staged V tile
            float x[8]; uint4 hp, lp;
#pragma unroll
            for (int j = 0; j < 8; ++j) {
                if (IS_F32) __builtin_memcpy(&x[j], &Rv.v[j], 4);
                else        x[j] = bf2f(Rv.v[j]);
            }
            split_pack(x, hp, lp);
            *(uint4*)(Vt + v_wo)      = hp;
            *(uint4*)(Vt + v_wo + 64) = lp;
        }
        __syncthreads();                     // (B) staging visible to all waves

        if (kt + 1 < nkt) {                  // prefetch next tile under compute
            if (is_ke) issue_ke<IS_F32>(Kv, PKv, base, kbase + BK, r_t, j8_t, Rke);
            else       issue_v <IS_F32>(Vv, base, kbase + BK, d_t, kg_t, Rv);
        }

        if (kbase <= qb_w + 15) {            // wave-uniform: tile has unmasked keys
            const bool do1 = (kbase + 16 <= qb_w + 15);
            const int c7 = c & 7;
            // ---- scores: S = (Q.K^T + PEq.PEk^T) * 1/8, split precision ----
            f32x4 s0 = {0,0,0,0}, s1 = {0,0,0,0};
#pragma unroll
            for (int ch = 0; ch < 4; ++ch) {
                const u16* Bp = (ch < 2) ? Kt : Et;
                const int sh = ((((ch & 1) * 4 + g) ^ c7)) * 8;
                const u16* r0 = Bp + c * 128;
                bf16x8 b0h = *(const bf16x8*)(r0 + sh);
                bf16x8 b0l = *(const bf16x8*)(r0 + sh + 64);
                s0 = MFMA(qa_h[ch], b0h, s0);
                s0 = MFMA(qa_h[ch], b0l, s0);
                s0 = MFMA(qa_l[ch], b0h, s0);
                if (do1) {
                    const u16* r1 = Bp + (c + 16) * 128;   // (c+16)&7 == c&7
                    bf16x8 b1h = *(const bf16x8*)(r1 + sh);
                    bf16x8 b1l = *(const bf16x8*)(r1 + sh + 64);
                    s1 = MFMA(qa_h[ch], b1h, s1);
                    s1 = MFMA(qa_h[ch], b1l, s1);
                    s1 = MFMA(qa_l[ch], b1h, s1);
                }
            }
            // ---- causal mask (C/D layout: row = 4g+i, col = c) ----
#pragma unroll
            for (int i = 0; i < 4; ++i) {
                const int r = qb_w + 4 * g + i;
                if (kbase + c > r)                s0[i] = -INFINITY;
                if (!do1 || kbase + 16 + c > r)   s1[i] = -INFINITY;
            }
            // ---- row max across the 16 lanes of this group ----
            float vm[4];
#pragma unroll
            for (int i = 0; i < 4; ++i) vm[i] = fmaxf(s0[i], s1[i]);
#pragma unroll
            for (int off = 1; off < 16; off <<= 1) {
#pragma unroll
                for (int i = 0; i < 4; ++i) vm[i] = fmaxf(vm[i], __shfl_xor(vm[i], off));
            }
            float al[4];
#pragma unroll
            for (int i = 0; i < 4; ++i) {
                float mn = fmaxf(mr[i], vm[i]);
                al[i] = __expf(mr[i] - mn);         // exp(-inf)=0 on first tile
                mr[i] = mn;
            }
            f32x4 p0, p1;
#pragma unroll
            for (int i = 0; i < 4; ++i) {
                p0[i] = __expf(s0[i] - mr[i]);      // masked -> exp(-inf)=0
                p1[i] = __expf(s1[i] - mr[i]);
            }
            float rs[4];
#pragma unroll
            for (int i = 0; i < 4; ++i) rs[i] = p0[i] + p1[i];
#pragma unroll
            for (int off = 1; off < 16; off <<= 1) {
#pragma unroll
                for (int i = 0; i < 4; ++i) rs[i] += __shfl_xor(rs[i], off);
            }
#pragma unroll
            for (int i = 0; i < 4; ++i) lr[i] = lr[i] * al[i] + rs[i];
#pragma unroll
            for (int df = 0; df < 4; ++df) {
#pragma unroll
                for (int i = 0; i < 4; ++i) acc[df][i] *= al[i];
            }
            // ---- P -> per-wave LDS (trunc hi/lo) to convert C- -> A-layout ----
            u16* pp = (u16*)Pb[w];
#pragma unroll
            for (int i = 0; i < 4; ++i) {
                const int rrp = 2 * g + (i >> 1);
                const int sb  = 4 * (i & 1);
                const int h3  = rrp & 7;
                u16* rowp = pp + rrp * 128 + c7;
                const float x0 = p0[i];              // named locals: vector elems
                const float x1 = p1[i];              // have no address
                u32 b0; __builtin_memcpy(&b0, &x0, 4);
                u32 h0 = b0 & 0xffff0000u; float h0f; __builtin_memcpy(&h0f, &h0, 4);
                float l0f = x0 - h0f; u32 l0; __builtin_memcpy(&l0, &l0f, 4);
                u32 b1; __builtin_memcpy(&b1, &x1, 4);
                u32 h1 = b1 & 0xffff0000u; float h1f; __builtin_memcpy(&h1f, &h1, 4);
                float l1f = x1 - h1f; u32 l1; __builtin_memcpy(&l1, &l1f, 4);
                const int s0i = (sb + (c >> 3)) ^ h3;
                const int s1i = (sb + 2 + (c >> 3)) ^ h3;
                rowp[s0i * 8]       = (u16)(b0 >> 16);
                rowp[(8 + s0i) * 8] = (u16)(l0 >> 16);
                rowp[s1i * 8]       = (u16)(b1 >> 16);
                rowp[(8 + s1i) * 8] = (u16)(l1 >> 16);
            }
            // in-wave ds_write -> ds_read: lockstep wave, compiler inserts lgkmcnt
            const int sv = ((4 * (c & 1) + g) ^ ((c >> 1) & 7)) * 8;  // P & V share formula
            const u16* pw = pp + (c >> 1) * 128;
            bf16x8 pa_h = *(const bf16x8*)(pw + sv);
            bf16x8 pa_l = *(const bf16x8*)(pw + sv + 64);
            // ---- PV: acc += P.V (split precision: PhVh + PhVl + PlVh) ----
#pragma unroll
            for (int df = 0; df < 4; ++df) {
                const u16* vw = Vt + (8 * df + (c >> 1)) * 128;
                bf16x8 vbh = *(const bf16x8*)(vw + sv);
                bf16x8 vbl = *(const bf16x8*)(vw + sv + 64);
                acc[df] = MFMA(pa_h, vbh, acc[df]);
                acc[df] = MFMA(pa_h, vbl, acc[df]);
                acc[df] = MFMA(pa_l, vbh, acc[df]);
            }
        }
    }

    // ---- epilogue ----
    float inv[4];
#pragma unroll
    for (int i = 0; i < 4; ++i) inv[i] = 1.f / lr[i];   // every row has >=1 valid key
    if (IS_F32) {
        float* o = (float*)Ov + base;
#pragma unroll
        for (int df = 0; df < 4; ++df)
#pragma unroll
            for (int i = 0; i < 4; ++i)
                o[(size_t)(qb_w + 4 * g + i) * D_DIM + 16 * df + c] = acc[df][i] * inv[i];
    } else {
        __hip_bfloat16* o = (__hip_bfloat16*)Ov + base;
#pragma unroll
        for (int df = 0; df < 4; ++df)
#pragma unroll
            for (int i = 0; i < 4; ++i)
                o[(size_t)(qb_w + 4 * g + i) * D_DIM + 16 * df + c] =
                    __float2bfloat16(acc[df][i] * inv[i]);
    }
}

extern "C" void kernel_launch(void* const* d_in, const int* in_sizes, int n_in,
                              void* d_out, int out_size, void* d_ws, size_t ws_size,
                              hipStream_t stream) {
    const void* q  = d_in[0];
    const void* k  = d_in[1];
    const void* v  = d_in[2];
    const void* pq = d_in[3];
    const void* pk = d_in[4];
    // d_in[5] = causal mask, recomputed analytically in-kernel.
    int* flag = (int*)d_ws;

    detect_dtype_kernel<<<1, 64, 0, stream>>>((const u16*)q, flag);

    dim3 grid(NQT / 2, 32);                  // 16 pairs x 32 heads = 512 blocks
    attn_pair<false><<<grid, 512, 0, stream>>>(q, k, v, pq, pk, d_out, flag);
    attn_pair<true ><<<grid, 512, 0, stream>>>(q, k, v, pq, pk, d_out, flag);
}

// Round 6
// 265.640 us; speedup vs baseline: 2.2223x; 1.1452x over previous
//
#include <hip/hip_runtime.h>
#include <hip/hip_bf16.h>

// B=2, H=16, L=2048, D=64. BH=32 flattened heads.
// MFMA flash attention, round 6: swapped QK^T + in-register P + LDS dbuf.
//  - Scores computed as S^T = mfma(K_frag, Q_frag): each lane holds one
//    query's scores -> softmax stats are per-lane SCALARS (2 shfl_xor vs 32).
//  - P redistribution to the PV A-fragment via 16 ds_bpermute (__shfl) in
//    registers; the 16KB Pb LDS buffer and its scalar-write round-trip die.
//  - K/E/V double-buffered (48KB): ONE barrier per trip; staging writes go
//    to buf^1 and overlap other waves' compute on buf.
//  - Keeps round-5's paired q-tiles (waves 0-3: qa, 4-7: 31-qa), rotation,
//    staging role split, swizzled LDS layouts, split-precision MFMA scheme.
// Runtime dtype detection kept (flag in d_ws); both instantiations launch,
// wrong one early-exits. mask input (d_in[5]) is pure causal -> analytic.

typedef unsigned short u16;
typedef unsigned int   u32;
typedef __attribute__((ext_vector_type(8))) short bf16x8;  // 8 bf16 (4 VGPR)
typedef __attribute__((ext_vector_type(4))) float f32x4;   // MFMA acc

#define L_SEQ 2048
#define D_DIM 64
#define BQ    64            // q rows per tile = 4 waves x 16
#define BK    32            // keys per tile
#define NQT   (L_SEQ / BQ)  // 32 q-tiles per head

__device__ __forceinline__ float bf2f(u32 lo16) {
    u32 u = lo16 << 16; float f; __builtin_memcpy(&f, &u, 4); return f;
}

__global__ void detect_dtype_kernel(const u16* __restrict__ q, int* __restrict__ flag) {
    const int lane = threadIdx.x;             // 64 threads, 1 block
    float x = fabsf(bf2f((u32)q[lane]));
    bool big = !(x <= 100.f);                 // fp32 mantissa bits look like wild bf16
    unsigned long long m = __ballot(big);
    if (lane == 0) *flag = (m != 0ull) ? 1 : 0;  // 1 = fp32, 0 = bf16
}

// ---- truncating hi/lo split of 8 f32 -> packed bf16 uint4 pair ----
__device__ __forceinline__ void split_pack(const float* x, uint4& h, uint4& l) {
    u32 xb[8], rb[8];
#pragma unroll
    for (int j = 0; j < 8; ++j) {
        __builtin_memcpy(&xb[j], &x[j], 4);
        u32 hb = xb[j] & 0xffff0000u;
        float hf; __builtin_memcpy(&hf, &hb, 4);
        float r = x[j] - hf;                  // exact residual of truncation
        __builtin_memcpy(&rb[j], &r, 4);
    }
    h.x = (xb[0] >> 16) | (xb[1] & 0xffff0000u);
    h.y = (xb[2] >> 16) | (xb[3] & 0xffff0000u);
    h.z = (xb[4] >> 16) | (xb[5] & 0xffff0000u);
    h.w = (xb[6] >> 16) | (xb[7] & 0xffff0000u);
    l.x = (rb[0] >> 16) | (rb[1] & 0xffff0000u);
    l.y = (rb[2] >> 16) | (rb[3] & 0xffff0000u);
    l.z = (rb[4] >> 16) | (rb[5] & 0xffff0000u);
    l.w = (rb[6] >> 16) | (rb[7] & 0xffff0000u);
}

template<bool IS_F32>
__device__ __forceinline__ void unpack8(const uint4& a, const uint4& b, float* x) {
    if (IS_F32) {
        u32 w[8] = {a.x, a.y, a.z, a.w, b.x, b.y, b.z, b.w};
#pragma unroll
        for (int j = 0; j < 8; ++j) __builtin_memcpy(&x[j], &w[j], 4);
    } else {
        u32 w[4] = {a.x, a.y, a.z, a.w};
#pragma unroll
        for (int j = 0; j < 4; ++j) {
            x[2*j]   = bf2f(w[j] & 0xffffu);
            x[2*j+1] = bf2f(w[j] >> 16);
        }
    }
}

struct StKE { uint4 k0, k1, e0, e1; };   // bf16 path uses k0/e0 only
struct StV  { u32 v[8]; };

template<bool IS_F32>
__device__ __forceinline__ void issue_ke(const void* Kv, const void* Ev,
        size_t base, int kbase, int r, int j8, StKE& R) {
    const size_t off = base + (size_t)(kbase + r) * D_DIM + j8 * 8;
    if (IS_F32) {
        const uint4* kp = (const uint4*)((const float*)Kv + off);
        R.k0 = kp[0]; R.k1 = kp[1];
        const uint4* ep = (const uint4*)((const float*)Ev + off);
        R.e0 = ep[0]; R.e1 = ep[1];
    } else {
        R.k0 = *(const uint4*)((const u16*)Kv + off);
        R.e0 = *(const uint4*)((const u16*)Ev + off);
    }
}

template<bool IS_F32>
__device__ __forceinline__ void issue_v(const void* Vv,
        size_t base, int kbase, int d, int kg, StV& R) {
    const size_t off = base + (size_t)(kbase + kg * 8) * D_DIM + d;
    if (IS_F32) {
        const u32* vp = (const u32*)((const float*)Vv + off);
#pragma unroll
        for (int j = 0; j < 8; ++j) R.v[j] = vp[j * D_DIM];   // one dim, 8 keys
    } else {
        const u16* vp = (const u16*)Vv + off;
#pragma unroll
        for (int j = 0; j < 8; ++j) R.v[j] = (u32)vp[j * D_DIM];
    }
}

#define MFMA(a, b, c) __builtin_amdgcn_mfma_f32_16x16x32_bf16((a), (b), (c), 0, 0, 0)

template<bool IS_F32>
__global__ __launch_bounds__(512, 4) void attn_pair(
    const void* __restrict__ Qv, const void* __restrict__ Kv,
    const void* __restrict__ Vv, const void* __restrict__ PQv,
    const void* __restrict__ PKv, void* __restrict__ Ov,
    const int* __restrict__ flag)
{
    if (((*flag) != 0) != IS_F32) return;    // wrong dtype for this instantiation

    const int bh   = blockIdx.y;
    const int qa   = ((int)blockIdx.x + bh) & 15;   // rotation balances CUs
    const int t    = threadIdx.x;
    const int w    = t >> 6;                 // wave 0..7
    const int lane = t & 63;
    const int g    = lane >> 4;              // 16-lane group 0..3
    const int c    = lane & 15;
    const size_t base = (size_t)bh * L_SEQ * D_DIM;
    const int qtile = (w < 4) ? qa : (31 - qa);     // light / heavy q-tile
    const int qb_w  = qtile * BQ + (w & 3) * 16;    // this wave's first q row
    const int nkt   = 64 - 2 * qa;           // heavy tile's k-tile count (covers light)

    // LDS: double-buffered swizzled tile images (rows 256B, 16B slots XOR'd).
    __shared__ __align__(16) u16 Kt[2][BK * 128];     // 16 KB
    __shared__ __align__(16) u16 Et[2][BK * 128];     // 16 KB
    __shared__ __align__(16) u16 Vt[2][32 * 128];     // 16 KB
    // total 48 KB -> 2 blocks/CU (grid is 2/CU anyway)

    // ---- Q & PE_Q fragments (pre-scaled by 1/8; exact power-of-2) ----
    // Used as the MFMA *B* operand now (layout identical to A).
    bf16x8 qa_h[4], qa_l[4];                 // ch 0,1 = Q d0=0,32 ; ch 2,3 = PE_Q
    {
        const int qrow = qb_w + c;
#pragma unroll
        for (int ch = 0; ch < 4; ++ch) {
            const void* src = (ch < 2) ? Qv : PQv;
            const int d0 = (ch & 1) * 32 + 8 * g;
            const size_t off = base + (size_t)qrow * D_DIM + d0;
            float x[8];
            if (IS_F32) {
                const uint4* gp = (const uint4*)((const float*)src + off);
                unpack8<true>(gp[0], gp[1], x);
            } else {
                uint4 a = *(const uint4*)((const u16*)src + off);
                unpack8<false>(a, a, x);
            }
#pragma unroll
            for (int j = 0; j < 8; ++j) x[j] *= 0.125f;
            uint4 hp, lp; split_pack(x, hp, lp);
            u32 hw[4] = {hp.x, hp.y, hp.z, hp.w}, lw[4] = {lp.x, lp.y, lp.z, lp.w};
#pragma unroll
            for (int j = 0; j < 4; ++j) {
                qa_h[ch][2*j]   = (short)(hw[j] & 0xffffu);
                qa_h[ch][2*j+1] = (short)(hw[j] >> 16);
                qa_l[ch][2*j]   = (short)(lw[j] & 0xffffu);
                qa_l[ch][2*j+1] = (short)(lw[j] >> 16);
            }
        }
    }

    float mr = -INFINITY, lr = 0.f;          // scalar stats (one query per lane)
    f32x4 acc[4];
#pragma unroll
    for (int df = 0; df < 4; ++df) acc[df] = (f32x4){0.f, 0.f, 0.f, 0.f};

    // ---- staging roles: waves 0-3 stage K+PE, waves 4-7 stage V ----
    const bool is_ke = (t < 256);
    const int ts   = t & 255;
    const int r_t  = ts >> 3;                // K/E: row (key) 0..31
    const int j8_t = ts & 7;                 // K/E: 8-elem chunk 0..7
    const int d_t  = ts & 63;                // V: dim 0..63
    const int kg_t = (ts >> 6) & 3;          // V: key chunk 0..3
    const int ke_wo = r_t * 128 + (j8_t ^ (r_t & 7)) * 8;           // hi; lo at +64
    const int v_rr  = d_t >> 1;
    const int v_wo  = v_rr * 128 + ((4 * (d_t & 1) + kg_t) ^ (v_rr & 7)) * 8;

    StKE Rke; StV Rv;

    auto stage_store = [&](int b) {
        if (is_ke) {
            float x[8]; uint4 hp, lp;
            unpack8<IS_F32>(Rke.k0, Rke.k1, x);
            split_pack(x, hp, lp);
            *(uint4*)(&Kt[b][0] + ke_wo)      = hp;
            *(uint4*)(&Kt[b][0] + ke_wo + 64) = lp;
            unpack8<IS_F32>(Rke.e0, Rke.e1, x);
            split_pack(x, hp, lp);
            *(uint4*)(&Et[b][0] + ke_wo)      = hp;
            *(uint4*)(&Et[b][0] + ke_wo + 64) = lp;
        } else {
            float x[8]; uint4 hp, lp;
#pragma unroll
            for (int j = 0; j < 8; ++j) {
                if (IS_F32) __builtin_memcpy(&x[j], &Rv.v[j], 4);
                else        x[j] = bf2f(Rv.v[j]);
            }
            split_pack(x, hp, lp);
            *(uint4*)(&Vt[b][0] + v_wo)      = hp;
            *(uint4*)(&Vt[b][0] + v_wo + 64) = lp;
        }
    };
    auto issue = [&](int kbase) {
        if (is_ke) issue_ke<IS_F32>(Kv, PKv, base, kbase, r_t, j8_t, Rke);
        else       issue_v <IS_F32>(Vv, base, kbase, d_t, kg_t, Rv);
    };

    // ---- prologue: tile 0 into buf 0; tile 1 in flight ----
    issue(0);
    stage_store(0);
    issue(BK);
    __syncthreads();

    const int c7 = c & 7;
    const int srcA = 32 * (g & 1) + c;       // P-shuffle sources (own column)
    const int srcB = srcA + 16;

    for (int kt = 0; kt < nkt; ++kt) {
        const int cur = kt & 1;
        const int kbase = kt * BK;

        if (kt + 1 < nkt) {                  // stage next tile into other buffer
            stage_store(cur ^ 1);
            if (kt + 2 < nkt) issue(kbase + 2 * BK);
        }

        if (kbase <= qb_w + 15) {            // wave-uniform: tile has unmasked keys
            const bool do1 = (kbase + 16 <= qb_w + 15);
            const u16* Ktc = &Kt[cur][0];
            const u16* Etc = &Et[cur][0];
            const u16* Vtc = &Vt[cur][0];
            // ---- scores: S^T = K.Q^T (+ PEk.PEq^T), split precision ----
            // Lane (g,c): s0[i] = S[key kbase+4g+i][query qb_w+c], s1: key+16.
            f32x4 s0 = {0,0,0,0}, s1 = {0,0,0,0};
#pragma unroll
            for (int ch = 0; ch < 4; ++ch) {
                const u16* Bp = (ch < 2) ? Ktc : Etc;
                const int sh = ((((ch & 1) * 4 + g) ^ c7)) * 8;
                const u16* r0 = Bp + c * 128;
                bf16x8 b0h = *(const bf16x8*)(r0 + sh);
                bf16x8 b0l = *(const bf16x8*)(r0 + sh + 64);
                s0 = MFMA(b0h, qa_h[ch], s0);    // Kh.Qh
                s0 = MFMA(b0l, qa_h[ch], s0);    // Kl.Qh
                s0 = MFMA(b0h, qa_l[ch], s0);    // Kh.Ql
                if (do1) {
                    const u16* r1 = Bp + (c + 16) * 128;   // (c+16)&7 == c&7
                    bf16x8 b1h = *(const bf16x8*)(r1 + sh);
                    bf16x8 b1l = *(const bf16x8*)(r1 + sh + 64);
                    s1 = MFMA(b1h, qa_h[ch], s1);
                    s1 = MFMA(b1l, qa_h[ch], s1);
                    s1 = MFMA(b1h, qa_l[ch], s1);
                }
            }
            // ---- causal mask (rows = keys now): key > query -> -inf ----
            const int qrow = qb_w + c;
#pragma unroll
            for (int i = 0; i < 4; ++i) {
                if (kbase + 4 * g + i > qrow)                s0[i] = -INFINITY;
                if (!do1 || kbase + 16 + 4 * g + i > qrow)   s1[i] = -INFINITY;
            }
            // ---- per-query (per-lane) softmax: in-lane + 2 shfl_xor ----
            float vm = fmaxf(fmaxf(fmaxf(s0[0], s0[1]), fmaxf(s0[2], s0[3])),
                             fmaxf(fmaxf(s1[0], s1[1]), fmaxf(s1[2], s1[3])));
            vm = fmaxf(vm, __shfl_xor(vm, 16));
            vm = fmaxf(vm, __shfl_xor(vm, 32));
            const float mn = fmaxf(mr, vm);
            const float al = __expf(mr - mn);    // exp(-inf)=0 on first tile
            mr = mn;
            float p0f[4], p1f[4];
#pragma unroll
            for (int i = 0; i < 4; ++i) {
                p0f[i] = __expf(s0[i] - mn);     // masked -> exp(-inf)=0
                p1f[i] = __expf(s1[i] - mn);
            }
            float rs = (p0f[0] + p0f[1]) + (p0f[2] + p0f[3])
                     + (p1f[0] + p1f[1]) + (p1f[2] + p1f[3]);
            rs += __shfl_xor(rs, 16);
            rs += __shfl_xor(rs, 32);
            lr = lr * al + rs;
            // ---- acc rescale: alpha for query 4g+i lives at lane 20g+i ----
            float al4[4];
#pragma unroll
            for (int i = 0; i < 4; ++i) al4[i] = __shfl(al, 20 * g + i);
#pragma unroll
            for (int df = 0; df < 4; ++df) {
#pragma unroll
                for (int i = 0; i < 4; ++i) acc[df][i] *= al4[i];
            }
            // ---- P -> PV A-fragment, fully in-register ----
            // Pack p (trunc hi|lo bf16) then shuffle within own column:
            // dest (g,c) takes keys 8g..8g+7 from lanes srcA/srcB, array by half.
            u32 w0[4], w1[4];
#pragma unroll
            for (int i = 0; i < 4; ++i) {
                const float x0 = p0f[i];
                u32 b0; __builtin_memcpy(&b0, &x0, 4);
                u32 h0 = b0 & 0xffff0000u; float h0f; __builtin_memcpy(&h0f, &h0, 4);
                float l0f = x0 - h0f; u32 l0; __builtin_memcpy(&l0, &l0f, 4);
                w0[i] = (b0 >> 16) | (l0 & 0xffff0000u);
                const float x1 = p1f[i];
                u32 b1; __builtin_memcpy(&b1, &x1, 4);
                u32 h1 = b1 & 0xffff0000u; float h1f; __builtin_memcpy(&h1f, &h1, 4);
                float l1f = x1 - h1f; u32 l1; __builtin_memcpy(&l1, &l1f, 4);
                w1[i] = (b1 >> 16) | (l1 & 0xffff0000u);
            }
            const bool lowhalf = (lane < 32);    // g<2 -> keys<16 -> p0 array
            bf16x8 pa_h, pa_l;
#pragma unroll
            for (int i = 0; i < 4; ++i) {
                u32 t0a = (u32)__shfl((int)w0[i], srcA);
                u32 t1a = (u32)__shfl((int)w1[i], srcA);
                u32 t0b = (u32)__shfl((int)w0[i], srcB);
                u32 t1b = (u32)__shfl((int)w1[i], srcB);
                u32 ha = lowhalf ? t0a : t1a;
                u32 hb = lowhalf ? t0b : t1b;
                pa_h[i]     = (short)(ha & 0xffffu);
                pa_h[4 + i] = (short)(hb & 0xffffu);
                pa_l[i]     = (short)(ha >> 16);
                pa_l[4 + i] = (short)(hb >> 16);
            }
            // ---- PV: acc += P.V (split precision: PhVh + PhVl + PlVh) ----
#pragma unroll
            for (int df = 0; df < 4; ++df) {
                const int sv = ((4 * (c & 1) + g) ^ ((c >> 1) & 7)) * 8;
                const u16* vw = Vtc + (8 * df + (c >> 1)) * 128;
                bf16x8 vbh = *(const bf16x8*)(vw + sv);
                bf16x8 vbl = *(const bf16x8*)(vw + sv + 64);
                acc[df] = MFMA(pa_h, vbh, acc[df]);
                acc[df] = MFMA(pa_h, vbl, acc[df]);
                acc[df] = MFMA(pa_l, vbh, acc[df]);
            }
        }
        __syncthreads();                     // end of trip: buf^1 now complete
    }

    // ---- epilogue: 1/l for query 4g+i lives at lane 20g+i ----
    float inv[4];
#pragma unroll
    for (int i = 0; i < 4; ++i) inv[i] = 1.f / __shfl(lr, 20 * g + i);
    if (IS_F32) {
        float* o = (float*)Ov + base;
#pragma unroll
        for (int df = 0; df < 4; ++df)
#pragma unroll
            for (int i = 0; i < 4; ++i)
                o[(size_t)(qb_w + 4 * g + i) * D_DIM + 16 * df + c] = acc[df][i] * inv[i];
    } else {
        __hip_bfloat16* o = (__hip_bfloat16*)Ov + base;
#pragma unroll
        for (int df = 0; df < 4; ++df)
#pragma unroll
            for (int i = 0; i < 4; ++i)
                o[(size_t)(qb_w + 4 * g + i) * D_DIM + 16 * df + c] =
                    __float2bfloat16(acc[df][i] * inv[i]);
    }
}

extern "C" void kernel_launch(void* const* d_in, const int* in_sizes, int n_in,
                              void* d_out, int out_size, void* d_ws, size_t ws_size,
                              hipStream_t stream) {
    const void* q  = d_in[0];
    const void* k  = d_in[1];
    const void* v  = d_in[2];
    const void* pq = d_in[3];
    const void* pk = d_in[4];
    // d_in[5] = causal mask, recomputed analytically in-kernel.
    int* flag = (int*)d_ws;

    detect_dtype_kernel<<<1, 64, 0, stream>>>((const u16*)q, flag);

    dim3 grid(NQT / 2, 32);                  // 16 pairs x 32 heads = 512 blocks
    attn_pair<false><<<grid, 512, 0, stream>>>(q, k, v, pq, pk, d_out, flag);
    attn_pair<true ><<<grid, 512, 0, stream>>>(q, k, v, pq, pk, d_out, flag);
}